// Round 13
// baseline (58.399 us; speedup 1.0000x reference)
//
#include <hip/hip_runtime.h>
#include <stdint.h>

// Problem constants
#define B_ 4
#define T_ 1024
#define D_ 1024
#define H_ 2048
#define E_ 8

// Device-coherent relaxed atomics — ONLY for tiny cross-block data inside
// one kernel (sbuf handoff to the last block, counter). Bulk data always
// travels cached across kernel boundaries (lessons of rounds 9/10/11).
#define AS(p, v) __hip_atomic_store((p), (v), __ATOMIC_RELAXED, __HIP_MEMORY_SCOPE_AGENT)

// Fire-and-forget global->LDS staging, 16B/lane. LDS dest wave-uniform.
__device__ __forceinline__ void stage16(const float* g, float* l) {
    __builtin_amdgcn_global_load_lds(
        (const __attribute__((address_space(1))) uint32_t*)g,
        (__attribute__((address_space(3))) uint32_t*)l, 16, 0, 0);
}

// Batched device-coherent 16B loads (4 at once, one drain) — last block's
// sbuf read. sc0 sc1 -> read at device coherence point.
__device__ __forceinline__ void load4x16_sc(const float* p0, const float* p1,
                                            const float* p2, const float* p3,
                                            float4& r0, float4& r1,
                                            float4& r2, float4& r3) {
    asm volatile(
        "global_load_dwordx4 %0, %4, off sc0 sc1\n\t"
        "global_load_dwordx4 %1, %5, off sc0 sc1\n\t"
        "global_load_dwordx4 %2, %6, off sc0 sc1\n\t"
        "global_load_dwordx4 %3, %7, off sc0 sc1\n\t"
        "s_waitcnt vmcnt(0)"
        : "=&v"(r0), "=&v"(r1), "=&v"(r2), "=&v"(r3)
        : "v"(p0), "v"(p1), "v"(p2), "v"(p3)
        : "memory");
}

// --------------------------------------------------------------------------
// Kernel A (round-8 champion, verbatim): w2sum[r] = sum_d w2_flat[r, d].
// 512 blocks x 256 thr; block = 32 rows = 8 tiles of 4 rows, triple-buffered
// rolling global_load_lds pipeline, wave-private (no barriers).
// --------------------------------------------------------------------------
__global__ __launch_bounds__(256) void w2sum_kernel(const float* __restrict__ w2,
                                                    float* __restrict__ w2sum) {
    __shared__ float buf[3][4 * D_];                   // 48 KB
    const int wid = threadIdx.x >> 6, lane = threadIdx.x & 63;
    const float* src = w2 + ((size_t)blockIdx.x * 32 + wid) * D_ + lane * 4;

#define A_STAGE(k)                                                        \
    {                                                                     \
        const float* s_ = src + (size_t)(k) * 4 * D_;                     \
        float* d_ = &buf[(k) % 3][wid * D_];                              \
        stage16(s_,       d_);       stage16(s_ + 256, d_ + 256);         \
        stage16(s_ + 512, d_ + 512); stage16(s_ + 768, d_ + 768);         \
    }

    A_STAGE(0); A_STAGE(1);
    float accs[8];
#pragma unroll
    for (int k = 0; k < 8; ++k) {
        if (k < 7) asm volatile("s_waitcnt vmcnt(4)" ::: "memory");
        else       asm volatile("s_waitcnt vmcnt(0)" ::: "memory");
        if (k < 6) A_STAGE(k + 2);
        const float* row = &buf[k % 3][wid * D_];
        float acc = 0.f;
#pragma unroll
        for (int j = 0; j < 4; ++j) {
            float4 a = *(const float4*)&row[j * 256 + lane * 4];
            acc += a.x + a.y + a.z + a.w;
        }
#pragma unroll
        for (int off = 32; off >= 1; off >>= 1) acc += __shfl_xor(acc, off, 64);
        accs[k] = acc;
    }
#undef A_STAGE
    if (lane == 0) {
        const int r0 = blockIdx.x * 32 + wid;
#pragma unroll
        for (int k = 0; k < 8; ++k) w2sum[r0 + k * 4] = accs[k];  // cached
    }
}

// --------------------------------------------------------------------------
// Kernel B (round-8 champion, verbatim): vT[d*E + e] = dot(w1[e,d,:],
// w2sum[e,:]). 512 blocks x 256 thr; block = expert bid>>6, rows
// d0=(bid&63)*16 as 4 tiles of 4 rows, double-buffered (64 KB). w2sum[e]
// fragment in 8 float4 regs (cached; A->B boundary provides coherence).
// --------------------------------------------------------------------------
__global__ __launch_bounds__(256) void v_build_kernel(const float* __restrict__ w1,
                                                      const float* __restrict__ w2sum,
                                                      const float* __restrict__ b1,
                                                      const float* __restrict__ b2,
                                                      float* __restrict__ vT,
                                                      float* __restrict__ c) {
    __shared__ float buf[2][4 * H_];                   // 64 KB
    const int bid = blockIdx.x;
    const int e   = bid >> 6;                          // 64 blocks/expert
    const int d0  = (bid & 63) * 16;
    const int wid = threadIdx.x >> 6, lane = threadIdx.x & 63;
    const float* src = w1 + ((size_t)e * D_ + d0 + wid) * H_ + lane * 4;

    const float4* wsp = (const float4*)(w2sum + (size_t)e * H_) + lane;
    float4 s0 = wsp[0],   s1 = wsp[64],  s2 = wsp[128], s3 = wsp[192],
           s4 = wsp[256], s5 = wsp[320], s6 = wsp[384], s7 = wsp[448];
    asm volatile("" ::: "memory");

#define B_STAGE(k)                                                         \
    {                                                                      \
        const float* s_ = src + (size_t)(k) * 4 * H_;                      \
        float* d_ = &buf[(k) & 1][wid * H_];                               \
        stage16(s_,        d_);        stage16(s_ + 256,  d_ + 256);       \
        stage16(s_ + 512,  d_ + 512);  stage16(s_ + 768,  d_ + 768);       \
        stage16(s_ + 1024, d_ + 1024); stage16(s_ + 1280, d_ + 1280);      \
        stage16(s_ + 1536, d_ + 1536); stage16(s_ + 1792, d_ + 1792);      \
    }

    B_STAGE(0); B_STAGE(1);
    float accs[4];
#pragma unroll
    for (int k = 0; k < 4; ++k) {
        if (k < 3) asm volatile("s_waitcnt vmcnt(8)" ::: "memory");
        else       asm volatile("s_waitcnt vmcnt(0)" ::: "memory");
        const float* row = &buf[k & 1][wid * H_];
        float acc;
        {
            float4 a0 = *(const float4*)&row[0 * 256 + lane * 4];
            float4 a1 = *(const float4*)&row[1 * 256 + lane * 4];
            float4 a2 = *(const float4*)&row[2 * 256 + lane * 4];
            float4 a3 = *(const float4*)&row[3 * 256 + lane * 4];
            float4 a4 = *(const float4*)&row[4 * 256 + lane * 4];
            float4 a5 = *(const float4*)&row[5 * 256 + lane * 4];
            float4 a6 = *(const float4*)&row[6 * 256 + lane * 4];
            float4 a7 = *(const float4*)&row[7 * 256 + lane * 4];
            acc = a0.x*s0.x + a0.y*s0.y + a0.z*s0.z + a0.w*s0.w
                + a1.x*s1.x + a1.y*s1.y + a1.z*s1.z + a1.w*s1.w
                + a2.x*s2.x + a2.y*s2.y + a2.z*s2.z + a2.w*s2.w
                + a3.x*s3.x + a3.y*s3.y + a3.z*s3.z + a3.w*s3.w
                + a4.x*s4.x + a4.y*s4.y + a4.z*s4.z + a4.w*s4.w
                + a5.x*s5.x + a5.y*s5.y + a5.z*s5.z + a5.w*s5.w
                + a6.x*s6.x + a6.y*s6.y + a6.z*s6.z + a6.w*s6.w
                + a7.x*s7.x + a7.y*s7.y + a7.z*s7.z + a7.w*s7.w;
        }
#pragma unroll
        for (int off = 32; off >= 1; off >>= 1) acc += __shfl_xor(acc, off, 64);
        accs[k] = acc;
        if (k < 2) B_STAGE(k + 2);
    }
#undef B_STAGE
    if (lane == 0) {
#pragma unroll
        for (int k = 0; k < 4; ++k)
            vT[(size_t)(d0 + k * 4 + wid) * E_ + e] = accs[k];  // cached
    }

    // c[e] = b1[e,:].w2sum[e,:] + sum_d b2[e,d]   (ws regs still live)
    if ((bid & 63) == 0 && wid == 0) {
        const float4* bp = (const float4*)(b1 + (size_t)e * H_) + lane;
        float4 q0 = bp[0],   q1 = bp[64],  q2 = bp[128], q3 = bp[192],
               q4 = bp[256], q5 = bp[320], q6 = bp[384], q7 = bp[448];
        float s = q0.x*s0.x + q0.y*s0.y + q0.z*s0.z + q0.w*s0.w
                + q1.x*s1.x + q1.y*s1.y + q1.z*s1.z + q1.w*s1.w
                + q2.x*s2.x + q2.y*s2.y + q2.z*s2.z + q2.w*s2.w
                + q3.x*s3.x + q3.y*s3.y + q3.z*s3.z + q3.w*s3.w
                + q4.x*s4.x + q4.y*s4.y + q4.z*s4.z + q4.w*s4.w
                + q5.x*s5.x + q5.y*s5.y + q5.z*s5.z + q5.w*s5.w
                + q6.x*s6.x + q6.y*s6.y + q6.z*s6.z + q6.w*s6.w
                + q7.x*s7.x + q7.y*s7.y + q7.z*s7.z + q7.w*s7.w;
        const float4* cp = (const float4*)(b2 + (size_t)e * D_) + lane;
#pragma unroll
        for (int j = 0; j < 4; ++j) {
            float4 bb = cp[j * 64];
            s += bb.x + bb.y + bb.z + bb.w;
        }
#pragma unroll
        for (int off = 32; off >= 1; off >>= 1) s += __shfl_xor(s, off, 64);
        if (lane == 0) c[e] = s;
    }
}

// --------------------------------------------------------------------------
// Kernel CD: round-8's token kernel VERBATIM (1 token/wave, 1024 blocks,
// d = lane + 64*k coalesced mapping) + fused log-softmax in the last block
// (counter + AS stores + batched sc16 reads — mechanism validated in R12).
// --------------------------------------------------------------------------
__global__ __launch_bounds__(256) void cd_kernel(
    const float* __restrict__ x,  const float* __restrict__ wg,
    const float* __restrict__ vT, const float* __restrict__ cbuf,
    float* __restrict__ sbuf, unsigned* __restrict__ ccnt,
    float* __restrict__ out)
{
    const int wid  = threadIdx.x >> 6;
    const int lane = threadIdx.x & 63;
    const int n = blockIdx.x * 4 + wid;
    const float* xr = x + (size_t)n * D_;

    float lg[E_] = {0,0,0,0,0,0,0,0};
    float dv[E_] = {0,0,0,0,0,0,0,0};

#pragma unroll
    for (int k = 0; k < D_ / 64; ++k) {                 // 16 iters, coalesced
        const int d = lane + 64 * k;
        float xv = xr[d];
        const float4* wgp = (const float4*)(wg + (size_t)d * E_);
        const float4* vp  = (const float4*)(vT + (size_t)d * E_);
        float4 g0 = wgp[0], g1 = wgp[1];
        float4 v0 = vp[0],  v1 = vp[1];
        lg[0] += xv * g0.x; lg[1] += xv * g0.y; lg[2] += xv * g0.z; lg[3] += xv * g0.w;
        lg[4] += xv * g1.x; lg[5] += xv * g1.y; lg[6] += xv * g1.z; lg[7] += xv * g1.w;
        dv[0] += xv * v0.x; dv[1] += xv * v0.y; dv[2] += xv * v0.z; dv[3] += xv * v0.w;
        dv[4] += xv * v1.x; dv[5] += xv * v1.y; dv[6] += xv * v1.z; dv[7] += xv * v1.w;
    }

#pragma unroll
    for (int off = 32; off >= 1; off >>= 1) {
#pragma unroll
        for (int q = 0; q < E_; ++q) {
            lg[q] += __shfl_xor(lg[q], off, 64);
            dv[q] += __shfl_xor(dv[q], off, 64);
        }
    }

    if (lane == 0) {
        // top-2, tie -> lower index (jax.lax.top_k semantics)
        float m0 = lg[0]; int i0 = 0;
#pragma unroll
        for (int q = 1; q < E_; ++q) if (lg[q] > m0) { m0 = lg[q]; i0 = q; }
        float m1 = -3.0e38f; int i1 = 0;
#pragma unroll
        for (int q = 0; q < E_; ++q) if (q != i0 && lg[q] > m1) { m1 = lg[q]; i1 = q; }
        float dv0 = 0.f, dv1 = 0.f, c0v = 0.f, c1v = 0.f;
#pragma unroll
        for (int q = 0; q < E_; ++q) {
            if (q == i0) { dv0 += dv[q]; c0v += cbuf[q]; }
            if (q == i1) { dv1 += dv[q]; c1v += cbuf[q]; }
        }
        float g1w = 1.f / (1.f + expf(m0 - m1));
        AS(&sbuf[n], (1.f - g1w) * (dv0 + c0v) + g1w * (dv1 + c1v));
    }

    // last-block handoff
    asm volatile("s_waitcnt vmcnt(0)" ::: "memory");
    __syncthreads();
    __shared__ int islast;
    if (threadIdx.x == 0) {
        unsigned old = __hip_atomic_fetch_add(ccnt, 1u, __ATOMIC_RELAXED, __HIP_MEMORY_SCOPE_AGENT);
        islast = (old == (unsigned)(gridDim.x - 1)) ? 1 : 0;
    }
    __syncthreads();
    if (!islast) return;

    {   // Phase D: 4 waves, one batch row each; batched sc16 sbuf reads
        const int brow = wid;
        const float* row = sbuf + (size_t)brow * T_;
        float4 v0, v1, v2, v3;
        load4x16_sc(row + lane * 4 + 0 * 256, row + lane * 4 + 1 * 256,
                    row + lane * 4 + 2 * 256, row + lane * 4 + 3 * 256,
                    v0, v1, v2, v3);
        float vals[16] = {v0.x, v0.y, v0.z, v0.w, v1.x, v1.y, v1.z, v1.w,
                          v2.x, v2.y, v2.z, v2.w, v3.x, v3.y, v3.z, v3.w};
        float mx = -3.0e38f;
#pragma unroll
        for (int k = 0; k < 16; ++k) mx = fmaxf(mx, vals[k]);
#pragma unroll
        for (int off = 32; off >= 1; off >>= 1) mx = fmaxf(mx, __shfl_xor(mx, off, 64));
        float sm = 0.f;
#pragma unroll
        for (int k = 0; k < 16; ++k) sm += expf(vals[k] - mx);
#pragma unroll
        for (int off = 32; off >= 1; off >>= 1) sm += __shfl_xor(sm, off, 64);
        float lse = mx + logf(sm);
        // vals[k] order: k = j*4+c maps to t = lane*4 + j*256 + c
#pragma unroll
        for (int j = 0; j < 4; ++j) {
            float4 o;
            o.x = vals[j * 4 + 0] - lse; o.y = vals[j * 4 + 1] - lse;
            o.z = vals[j * 4 + 2] - lse; o.w = vals[j * 4 + 3] - lse;
            *(float4*)&out[(size_t)brow * T_ + lane * 4 + j * 256] = o;
        }
    }
}

// ---------------------------------------------------------------------------
extern "C" void kernel_launch(void* const* d_in, const int* in_sizes, int n_in,
                              void* d_out, int out_size, void* d_ws, size_t ws_size,
                              hipStream_t stream) {
    const float* x  = (const float*)d_in[0];   // [B, T, D]
    const float* wg = (const float*)d_in[1];   // [D, E]
    const float* w1 = (const float*)d_in[2];   // [E, D, H]
    const float* b1 = (const float*)d_in[3];   // [E, H]
    const float* w2 = (const float*)d_in[4];   // [E, H, D]
    const float* b2 = (const float*)d_in[5];   // [E, D]
    float* out = (float*)d_out;                // [B, T]

    float* ws     = (float*)d_ws;
    float* w2sum  = ws;                        // E*H = 16384 floats
    float* vT     = ws + 16384;                // D*E =  8192 floats ([D][E])
    float* cbuf   = ws + 24576;                // E
    float* sbuf   = ws + 24592;                // N = 4096
    unsigned* cnt = (unsigned*)(ws + 28688);   // ccnt

    // zero the CD completion counter (4 B memset node, graph-capturable)
    hipMemsetAsync(cnt, 0, sizeof(unsigned), stream);

    // A: 16384 rows, 32 rows/block (8-tile rolling pipeline) -> 512 blocks
    w2sum_kernel<<<dim3(512), dim3(256), 0, stream>>>(w2, w2sum);
    // B: 8192 rows, 16 rows/block (4-tile rolling pipeline) -> 512 blocks
    v_build_kernel<<<dim3(512), dim3(256), 0, stream>>>(w1, w2sum, b1, b2, vT, cbuf);
    // CD: 4096 tokens, 1/wave -> 1024 blocks; last block does log-softmax
    cd_kernel<<<dim3(1024), dim3(256), 0, stream>>>(x, wg, vT, cbuf, sbuf, cnt, out);
}

// Round 14
// 41.612 us; speedup vs baseline: 1.4034x; 1.4034x over previous
//
#include <hip/hip_runtime.h>
#include <stdint.h>

// Problem constants
#define B_ 4
#define T_ 1024
#define D_ 1024
#define H_ 2048
#define E_ 8

// Fire-and-forget global->LDS staging, 16B/lane. LDS dest wave-uniform.
__device__ __forceinline__ void stage16(const float* g, float* l) {
    __builtin_amdgcn_global_load_lds(
        (const __attribute__((address_space(1))) uint32_t*)g,
        (__attribute__((address_space(3))) uint32_t*)l, 16, 0, 0);
}

// --------------------------------------------------------------------------
// Kernel A (round-8 champion, verbatim): w2sum[r] = sum_d w2_flat[r, d].
// 512 blocks x 256 thr; block = 32 rows = 8 tiles of 4 rows, triple-buffered
// rolling global_load_lds pipeline, wave-private (no barriers).
// --------------------------------------------------------------------------
__global__ __launch_bounds__(256) void w2sum_kernel(const float* __restrict__ w2,
                                                    float* __restrict__ w2sum) {
    __shared__ float buf[3][4 * D_];                   // 48 KB
    const int wid = threadIdx.x >> 6, lane = threadIdx.x & 63;
    const float* src = w2 + ((size_t)blockIdx.x * 32 + wid) * D_ + lane * 4;

#define A_STAGE(k)                                                        \
    {                                                                     \
        const float* s_ = src + (size_t)(k) * 4 * D_;                     \
        float* d_ = &buf[(k) % 3][wid * D_];                              \
        stage16(s_,       d_);       stage16(s_ + 256, d_ + 256);         \
        stage16(s_ + 512, d_ + 512); stage16(s_ + 768, d_ + 768);         \
    }

    A_STAGE(0); A_STAGE(1);
    float accs[8];
#pragma unroll
    for (int k = 0; k < 8; ++k) {
        if (k < 7) asm volatile("s_waitcnt vmcnt(4)" ::: "memory");
        else       asm volatile("s_waitcnt vmcnt(0)" ::: "memory");
        if (k < 6) A_STAGE(k + 2);
        const float* row = &buf[k % 3][wid * D_];
        float acc = 0.f;
#pragma unroll
        for (int j = 0; j < 4; ++j) {
            float4 a = *(const float4*)&row[j * 256 + lane * 4];
            acc += a.x + a.y + a.z + a.w;
        }
#pragma unroll
        for (int off = 32; off >= 1; off >>= 1) acc += __shfl_xor(acc, off, 64);
        accs[k] = acc;
    }
#undef A_STAGE
    if (lane == 0) {
        const int r0 = blockIdx.x * 32 + wid;
#pragma unroll
        for (int k = 0; k < 8; ++k) w2sum[r0 + k * 4] = accs[k];
    }
}

// --------------------------------------------------------------------------
// Kernel B (round-8 champion, verbatim): vT[d*E + e] = dot(w1[e,d,:],
// w2sum[e,:]). 512 blocks x 256 thr; block = expert bid>>6, rows
// d0=(bid&63)*16 as 4 tiles of 4 rows, double-buffered (64 KB). w2sum[e]
// fragment in 8 float4 regs (cached; A->B boundary provides coherence).
// --------------------------------------------------------------------------
__global__ __launch_bounds__(256) void v_build_kernel(const float* __restrict__ w1,
                                                      const float* __restrict__ w2sum,
                                                      const float* __restrict__ b1,
                                                      const float* __restrict__ b2,
                                                      float* __restrict__ vT,
                                                      float* __restrict__ c) {
    __shared__ float buf[2][4 * H_];                   // 64 KB
    const int bid = blockIdx.x;
    const int e   = bid >> 6;                          // 64 blocks/expert
    const int d0  = (bid & 63) * 16;
    const int wid = threadIdx.x >> 6, lane = threadIdx.x & 63;
    const float* src = w1 + ((size_t)e * D_ + d0 + wid) * H_ + lane * 4;

    const float4* wsp = (const float4*)(w2sum + (size_t)e * H_) + lane;
    float4 s0 = wsp[0],   s1 = wsp[64],  s2 = wsp[128], s3 = wsp[192],
           s4 = wsp[256], s5 = wsp[320], s6 = wsp[384], s7 = wsp[448];
    asm volatile("" ::: "memory");

#define B_STAGE(k)                                                         \
    {                                                                      \
        const float* s_ = src + (size_t)(k) * 4 * H_;                      \
        float* d_ = &buf[(k) & 1][wid * H_];                               \
        stage16(s_,        d_);        stage16(s_ + 256,  d_ + 256);       \
        stage16(s_ + 512,  d_ + 512);  stage16(s_ + 768,  d_ + 768);       \
        stage16(s_ + 1024, d_ + 1024); stage16(s_ + 1280, d_ + 1280);      \
        stage16(s_ + 1536, d_ + 1536); stage16(s_ + 1792, d_ + 1792);      \
    }

    B_STAGE(0); B_STAGE(1);
    float accs[4];
#pragma unroll
    for (int k = 0; k < 4; ++k) {
        if (k < 3) asm volatile("s_waitcnt vmcnt(8)" ::: "memory");
        else       asm volatile("s_waitcnt vmcnt(0)" ::: "memory");
        const float* row = &buf[k & 1][wid * H_];
        float acc;
        {
            float4 a0 = *(const float4*)&row[0 * 256 + lane * 4];
            float4 a1 = *(const float4*)&row[1 * 256 + lane * 4];
            float4 a2 = *(const float4*)&row[2 * 256 + lane * 4];
            float4 a3 = *(const float4*)&row[3 * 256 + lane * 4];
            float4 a4 = *(const float4*)&row[4 * 256 + lane * 4];
            float4 a5 = *(const float4*)&row[5 * 256 + lane * 4];
            float4 a6 = *(const float4*)&row[6 * 256 + lane * 4];
            float4 a7 = *(const float4*)&row[7 * 256 + lane * 4];
            acc = a0.x*s0.x + a0.y*s0.y + a0.z*s0.z + a0.w*s0.w
                + a1.x*s1.x + a1.y*s1.y + a1.z*s1.z + a1.w*s1.w
                + a2.x*s2.x + a2.y*s2.y + a2.z*s2.z + a2.w*s2.w
                + a3.x*s3.x + a3.y*s3.y + a3.z*s3.z + a3.w*s3.w
                + a4.x*s4.x + a4.y*s4.y + a4.z*s4.z + a4.w*s4.w
                + a5.x*s5.x + a5.y*s5.y + a5.z*s5.z + a5.w*s5.w
                + a6.x*s6.x + a6.y*s6.y + a6.z*s6.z + a6.w*s6.w
                + a7.x*s7.x + a7.y*s7.y + a7.z*s7.z + a7.w*s7.w;
        }
#pragma unroll
        for (int off = 32; off >= 1; off >>= 1) acc += __shfl_xor(acc, off, 64);
        accs[k] = acc;
        if (k < 2) B_STAGE(k + 2);
    }
#undef B_STAGE
    if (lane == 0) {
#pragma unroll
        for (int k = 0; k < 4; ++k)
            vT[(size_t)(d0 + k * 4 + wid) * E_ + e] = accs[k];
    }

    // c[e] = b1[e,:].w2sum[e,:] + sum_d b2[e,d]   (ws regs still live)
    if ((bid & 63) == 0 && wid == 0) {
        const float4* bp = (const float4*)(b1 + (size_t)e * H_) + lane;
        float4 q0 = bp[0],   q1 = bp[64],  q2 = bp[128], q3 = bp[192],
               q4 = bp[256], q5 = bp[320], q6 = bp[384], q7 = bp[448];
        float s = q0.x*s0.x + q0.y*s0.y + q0.z*s0.z + q0.w*s0.w
                + q1.x*s1.x + q1.y*s1.y + q1.z*s1.z + q1.w*s1.w
                + q2.x*s2.x + q2.y*s2.y + q2.z*s2.z + q2.w*s2.w
                + q3.x*s3.x + q3.y*s3.y + q3.z*s3.z + q3.w*s3.w
                + q4.x*s4.x + q4.y*s4.y + q4.z*s4.z + q4.w*s4.w
                + q5.x*s5.x + q5.y*s5.y + q5.z*s5.z + q5.w*s5.w
                + q6.x*s6.x + q6.y*s6.y + q6.z*s6.z + q6.w*s6.w
                + q7.x*s7.x + q7.y*s7.y + q7.z*s7.z + q7.w*s7.w;
        const float4* cp = (const float4*)(b2 + (size_t)e * D_) + lane;
#pragma unroll
        for (int j = 0; j < 4; ++j) {
            float4 bb = cp[j * 64];
            s += bb.x + bb.y + bb.z + bb.w;
        }
#pragma unroll
        for (int off = 32; off >= 1; off >>= 1) s += __shfl_xor(s, off, 64);
        if (lane == 0) c[e] = s;
    }
}

// --------------------------------------------------------------------------
// Kernel C (NEW): LDS-staged gating. 256 blocks x 256 thr; block stages
// wg (32 KB) + vT (32 KB) into LDS ONCE, then its 4 waves each process
// 4 tokens. Conflict-free LDS reads: at step k, lane l reads the 16B unit
// 2*(32k)+l -> the wave reads 1 KB CONTIGUOUS LDS (rows 32k+(l>>1), col
// group (l&1)). Butterfly reduce over lane bits [5:1]; lane 0 pulls the
// other col group from lane 1. x read directly from global (L3-fed,
// pair-broadcast). Replaces ~550 MB of L2 wg/vT traffic with LDS reads.
// --------------------------------------------------------------------------
__global__ __launch_bounds__(256) void token_kernel(
    const float* __restrict__ x,  const float* __restrict__ wg,
    const float* __restrict__ vT, const float* __restrict__ cbuf,
    float* __restrict__ sbuf)
{
    __shared__ float wgl[D_ * E_];   // 32 KB  [d][e]
    __shared__ float vtl[D_ * E_];   // 32 KB  [d][e]
    const int wid = threadIdx.x >> 6, lane = threadIdx.x & 63;

    // stage wg, vT (contiguous; 8 rounds x 4 waves x 1 KB each)
#pragma unroll
    for (int r = 0; r < 8; ++r) {
        int base = r * 1024 + wid * 256;
        stage16(wg + base + lane * 4, wgl + base);
        stage16(vT + base + lane * 4, vtl + base);
    }
    asm volatile("s_waitcnt vmcnt(0)" ::: "memory");
    __syncthreads();

    const int half = lane & 1;       // 0 -> expert cols 0-3, 1 -> cols 4-7
    const int rrow = lane >> 1;      // row residue mod 32

#pragma unroll
    for (int t = 0; t < 4; ++t) {
        const int n = blockIdx.x * 16 + wid * 4 + t;
        const float* xg = x + (size_t)n * D_ + rrow;
        float ag0 = 0.f, ag1 = 0.f, ag2 = 0.f, ag3 = 0.f;
        float av0 = 0.f, av1 = 0.f, av2 = 0.f, av3 = 0.f;
#pragma unroll
        for (int k = 0; k < 32; ++k) {
            float xs = xg[32 * k];                       // x[n][32k + rrow]
            const int o = (32 * k + rrow) * 8 + half * 4;
            float4 w4 = *(const float4*)&wgl[o];
            float4 v4 = *(const float4*)&vtl[o];
            ag0 += xs * w4.x; ag1 += xs * w4.y; ag2 += xs * w4.z; ag3 += xs * w4.w;
            av0 += xs * v4.x; av1 += xs * v4.y; av2 += xs * v4.z; av3 += xs * v4.w;
        }
        // reduce over lane bits [5:1] (rows); every lane ends with its
        // col-group's full sums
#pragma unroll
        for (int off = 2; off <= 32; off <<= 1) {
            ag0 += __shfl_xor(ag0, off, 64); ag1 += __shfl_xor(ag1, off, 64);
            ag2 += __shfl_xor(ag2, off, 64); ag3 += __shfl_xor(ag3, off, 64);
            av0 += __shfl_xor(av0, off, 64); av1 += __shfl_xor(av1, off, 64);
            av2 += __shfl_xor(av2, off, 64); av3 += __shfl_xor(av3, off, 64);
        }
        // lane 1 holds cols 4-7; pull to all lanes, lane 0 finishes
        float g4 = __shfl(ag0, 1, 64), g5 = __shfl(ag1, 1, 64),
              g6 = __shfl(ag2, 1, 64), g7 = __shfl(ag3, 1, 64);
        float h4 = __shfl(av0, 1, 64), h5 = __shfl(av1, 1, 64),
              h6 = __shfl(av2, 1, 64), h7 = __shfl(av3, 1, 64);
        if (lane == 0) {
            float lg[E_] = {ag0, ag1, ag2, ag3, g4, g5, g6, g7};
            float dv[E_] = {av0, av1, av2, av3, h4, h5, h6, h7};
            // top-2, tie -> lower index (jax.lax.top_k semantics)
            float m0 = lg[0]; int i0 = 0;
#pragma unroll
            for (int q = 1; q < E_; ++q) if (lg[q] > m0) { m0 = lg[q]; i0 = q; }
            float m1 = -3.0e38f; int i1 = 0;
#pragma unroll
            for (int q = 0; q < E_; ++q) if (q != i0 && lg[q] > m1) { m1 = lg[q]; i1 = q; }
            float dv0 = 0.f, dv1 = 0.f, c0v = 0.f, c1v = 0.f;
#pragma unroll
            for (int q = 0; q < E_; ++q) {
                if (q == i0) { dv0 += dv[q]; c0v += cbuf[q]; }
                if (q == i1) { dv1 += dv[q]; c1v += cbuf[q]; }
            }
            float g1w = 1.f / (1.f + expf(m0 - m1));
            sbuf[n] = (1.f - g1w) * (dv0 + c0v) + g1w * (dv1 + c1v);
        }
    }
}

// --------------------------------------------------------------------------
// Kernel D (round-8 verbatim): out[b,t] = s[b,t] - logsumexp_t(s[b,:]).
// One block, 4 waves, wave per batch row; 16 values per lane.
// --------------------------------------------------------------------------
__global__ __launch_bounds__(256) void lsm_kernel(const float* __restrict__ s,
                                                  float* __restrict__ out) {
    int brow = threadIdx.x >> 6;
    int lane = threadIdx.x & 63;
    const float* row = s + (size_t)brow * T_;
    float vals[16];
    float mx = -3.0e38f;
#pragma unroll
    for (int k = 0; k < 16; ++k) {
        vals[k] = row[lane + 64 * k];
        mx = fmaxf(mx, vals[k]);
    }
#pragma unroll
    for (int off = 32; off >= 1; off >>= 1) mx = fmaxf(mx, __shfl_xor(mx, off, 64));
    float sm = 0.f;
#pragma unroll
    for (int k = 0; k < 16; ++k) sm += expf(vals[k] - mx);
#pragma unroll
    for (int off = 32; off >= 1; off >>= 1) sm += __shfl_xor(sm, off, 64);
    float lse = mx + logf(sm);
#pragma unroll
    for (int k = 0; k < 16; ++k) out[(size_t)brow * T_ + lane + 64 * k] = vals[k] - lse;
}

// ---------------------------------------------------------------------------
extern "C" void kernel_launch(void* const* d_in, const int* in_sizes, int n_in,
                              void* d_out, int out_size, void* d_ws, size_t ws_size,
                              hipStream_t stream) {
    const float* x  = (const float*)d_in[0];   // [B, T, D]
    const float* wg = (const float*)d_in[1];   // [D, E]
    const float* w1 = (const float*)d_in[2];   // [E, D, H]
    const float* b1 = (const float*)d_in[3];   // [E, H]
    const float* w2 = (const float*)d_in[4];   // [E, H, D]
    const float* b2 = (const float*)d_in[5];   // [E, D]
    float* out = (float*)d_out;                // [B, T]

    float* ws     = (float*)d_ws;
    float* w2sum  = ws;                        // E*H = 16384 floats
    float* vT     = ws + 16384;                // D*E =  8192 floats ([D][E])
    float* cbuf   = ws + 24576;                // E
    float* sbuf   = ws + 24592;                // N = 4096

    // A: 16384 rows, 32 rows/block (8-tile rolling pipeline) -> 512 blocks
    w2sum_kernel<<<dim3(512), dim3(256), 0, stream>>>(w2, w2sum);
    // B: 8192 rows, 16 rows/block (4-tile rolling pipeline) -> 512 blocks
    v_build_kernel<<<dim3(512), dim3(256), 0, stream>>>(w1, w2sum, b1, b2, vT, cbuf);
    // C: 4096 tokens, 16/block, wg+vT LDS-staged -> 256 blocks
    token_kernel<<<dim3(256), dim3(256), 0, stream>>>(x, wg, vT, cbuf, sbuf);
    // D: log-softmax over T per batch row, single block
    lsm_kernel<<<dim3(1), dim3(256), 0, stream>>>(sbuf, out);
}